// Round 11
// baseline (134.805 us; speedup 1.0000x reference)
//
#include <hip/hip_runtime.h>
#include <hip/hip_bf16.h>
#include <math.h>

#define LATENT 256
#define HIDDEN 512
#define NFD    64
#define MAXN   50
#define BATCH  128
#define NPAIR  2450   // 50*49
#define PTILE  64
#define NTILES 39     // ceil(2450/64)

typedef __attribute__((ext_vector_type(8))) _Float16 f16x8;
typedef __attribute__((ext_vector_type(4))) float f32x4;
typedef __attribute__((ext_vector_type(4))) unsigned int u32x4;

__device__ __forceinline__ float sigmoidf_(float x) {
    return 1.0f / (1.0f + expf(-x));
}
__device__ __forceinline__ f16x8 build_e1(f16x8 ui, f16x8 uj) {
    f16x8 s = ui + uj;
    return __builtin_elementwise_max(s, (f16x8)(_Float16)0);
}
__device__ __forceinline__ void gll16(const void* g, void* l) {
    __builtin_amdgcn_global_load_lds(
        (const __attribute__((address_space(1))) void*)g,
        (__attribute__((address_space(3))) void*)l, 16, 0, 0);
}
__device__ __forceinline__ u32x4 pack8(float4 a, float4 b) {
    f16x8 h;
    h[0] = (_Float16)a.x; h[1] = (_Float16)a.y;
    h[2] = (_Float16)a.z; h[3] = (_Float16)a.w;
    h[4] = (_Float16)b.x; h[5] = (_Float16)b.y;
    h[6] = (_Float16)b.z; h[7] = (_Float16)b.w;
    return __builtin_bit_cast(u32x4, h);
}

// ---------------------------------------------------------------------------
// K1 prologue: roles by blockIdx.x:
//  x<16        : fp32 gemm -> h1h fp16 (relu, n0<512) / Abc f32 (+c1, n0>=512)
//  16<=x<48    : E2 -> E2t chunk-major fp16 (slots 32 x 2y)
//  x>=48       : linear fp16 cvts: W2h | W3h | E1ih | E1jh (480 x 2y slots)
// ---------------------------------------------------------------------------
__global__ __launch_bounds__(256) void prologue_a(
    const float* __restrict__ z,
    const float* __restrict__ W1, const float* __restrict__ b1,
    const float* __restrict__ E1, const float* __restrict__ c1,
    const float* __restrict__ E2, const float* __restrict__ W2,
    const float* __restrict__ W3,
    unsigned short* __restrict__ E2t,
    unsigned short* __restrict__ W2h,
    unsigned short* __restrict__ W3h,
    unsigned short* __restrict__ E1ih,
    unsigned short* __restrict__ E1jh,
    unsigned short* __restrict__ h1h, float* __restrict__ Abc)
{
    const int tid = threadIdx.x;

    if (blockIdx.x >= 48) {   // linear cvts
        int slot = (blockIdx.x - 48) * 2 + blockIdx.y;   // 0..959
        int e = (slot * 256 + tid) * 8;
        const float* src;
        unsigned short* dst;
        if (e < 262144) { src = W2 + e; dst = W2h + e; }
        else if (e < 1900544) { int l = e - 262144; src = W3 + l; dst = W3h + l; }
        else if (e < 1933312) {
            int l = e - 1900544; int row = l >> 6, col = l & 63;
            src = E1 + row * 384 + 256 + col; dst = E1ih + l;
        } else {
            int l = e - 1933312; int row = l >> 6, col = l & 63;
            src = E1 + row * 384 + 320 + col; dst = E1jh + l;
        }
        float4 a = *(const float4*)src;
        float4 b = *(const float4*)(src + 4);
        *(u32x4*)dst = pack8(a, b);
        return;
    }

    if (blockIdx.x >= 16) {   // E2 -> chunk-major fp16
        int idx = ((blockIdx.x - 16) + blockIdx.y * 32) * 256 + tid;  // 16384
        int g  = idx & 255;
        int kc = idx >> 8;
        float4 a = *(const float4*)&E2[(size_t)g * 512 + kc * 8];
        float4 b = *(const float4*)&E2[(size_t)g * 512 + kc * 8 + 4];
        *(u32x4*)(E2t + (size_t)idx * 8) = pack8(a, b);
        return;
    }

    __shared__ __align__(16) float As[16][68];
    __shared__ __align__(16) float Bs[16][68];

    const int m0 = blockIdx.y * 64;
    const int n0 = blockIdx.x * 64;          // 0..1023
    const bool isE = n0 >= 512;
    const float* Bp = isE ? E1 + (size_t)(n0 - 512) * 384 : W1 + (size_t)n0 * 256;
    const int ldb = isE ? 384 : 256;

    const int sr = tid >> 2;
    const int kc = (tid & 3) * 4;
    const int tx = tid & 15;
    const int ty = tid >> 4;

    float acc[4][4] = {};

    for (int k0 = 0; k0 < 256; k0 += 16) {
        float4 a4 = *(const float4*)&z[(size_t)(m0 + sr) * 256 + k0 + kc];
        As[kc + 0][sr] = a4.x; As[kc + 1][sr] = a4.y;
        As[kc + 2][sr] = a4.z; As[kc + 3][sr] = a4.w;
        float4 b4 = *(const float4*)&Bp[(size_t)sr * ldb + k0 + kc];
        Bs[kc + 0][sr] = b4.x; Bs[kc + 1][sr] = b4.y;
        Bs[kc + 2][sr] = b4.z; Bs[kc + 3][sr] = b4.w;
        __syncthreads();
        #pragma unroll
        for (int k = 0; k < 16; ++k) {
            float av[4], bv[4];
            *(float4*)av = *(const float4*)&As[k][ty * 4];
            *(float4*)bv = *(const float4*)&Bs[k][tx * 4];
            #pragma unroll
            for (int r = 0; r < 4; ++r)
                #pragma unroll
                for (int c = 0; c < 4; ++c)
                    acc[r][c] = fmaf(av[r], bv[c], acc[r][c]);
        }
        __syncthreads();
    }

    #pragma unroll
    for (int r = 0; r < 4; ++r) {
        int gm = m0 + ty * 4 + r;
        #pragma unroll
        for (int c = 0; c < 4; ++c) {
            int gn = n0 + tx * 4 + c;
            if (isE) {
                int gl = gn - 512;
                Abc[(size_t)gm * 512 + gl] = acc[r][c] + c1[gl];
            } else {
                float v = fmaxf(acc[r][c] + b1[gn], 0.f);
                h1h[(size_t)gm * 512 + gn] =
                    __builtin_bit_cast(unsigned short, (_Float16)v);
            }
        }
    }
}

// ---------------------------------------------------------------------------
// K2: h2h = relu(h1h @ W2h^T + b2), fp16 MFMA. grid (8,2): n0=64x, m0=64y.
// ---------------------------------------------------------------------------
__global__ __launch_bounds__(256) void h2_gemm(
    const unsigned short* __restrict__ h1h,
    const unsigned short* __restrict__ W2h,
    const float* __restrict__ b2,
    unsigned short* __restrict__ h2h)
{
    __shared__ unsigned short Ah[3][2048];   // 64x32 fp16 per buf
    __shared__ unsigned short Bh[3][2048];

    const int tid = threadIdx.x;
    const int lane = tid & 63;
    const int w = tid >> 6;
    const int ln = lane & 15;
    const int hi = lane >> 4;
    const int m0 = blockIdx.y * 64;
    const int n0 = blockIdx.x * 64;

    const int srow = lane >> 2;             // 0..15 row within wave's 16
    const int scol = (lane & 3) * 8;
    const unsigned short* gA = h1h + (size_t)(m0 + 16 * w + srow) * 512 + scol;
    const unsigned short* gB = W2h + (size_t)(n0 + 16 * w + srow) * 512 + scol;
    unsigned short* lA = (unsigned short*)&Ah[0][0] + 512 * w;   // + buf*2048
    unsigned short* lB = (unsigned short*)&Bh[0][0] + 512 * w;

    f32x4 acc[4] = {};

    gll16(gA,      lA);          gll16(gB,      lB);
    gll16(gA + 32, lA + 2048);   gll16(gB + 32, lB + 2048);
    asm volatile("s_waitcnt vmcnt(2) lgkmcnt(0)\n\ts_barrier" ::: "memory");

    #pragma unroll
    for (int ks = 0; ks < 16; ++ks) {
        if (ks < 14) {
            const int bn = (ks + 2) % 3;
            gll16(gA + (ks + 2) * 32, lA + bn * 2048);
            gll16(gB + (ks + 2) * 32, lB + bn * 2048);
        }
        const int bb = ks % 3;
        f16x8 af = *(const f16x8*)&Ah[bb][(16 * w + ln) * 32 + hi * 8];
        f16x8 bf[4];
        #pragma unroll
        for (int ni = 0; ni < 4; ++ni)
            bf[ni] = *(const f16x8*)&Bh[bb][(16 * ni + ln) * 32 + hi * 8];
        #pragma unroll
        for (int ni = 0; ni < 4; ++ni)
            acc[ni] = __builtin_amdgcn_mfma_f32_16x16x32_f16(af, bf[ni], acc[ni], 0, 0, 0);
        if (ks < 14) {
            asm volatile("s_waitcnt vmcnt(2) lgkmcnt(0)\n\ts_barrier" ::: "memory");
        } else if (ks == 14) {
            asm volatile("s_waitcnt vmcnt(0) lgkmcnt(0)\n\ts_barrier" ::: "memory");
        }
    }

    #pragma unroll
    for (int ni = 0; ni < 4; ++ni) {
        int gn = n0 + 16 * ni + ln;
        float bias = b2[gn];
        #pragma unroll
        for (int r = 0; r < 4; ++r) {
            int gm = m0 + 16 * w + 4 * hi + r;
            float v = fmaxf(acc[ni][r] + bias, 0.f);
            h2h[(size_t)gm * 512 + gn] =
                __builtin_bit_cast(unsigned short, (_Float16)v);
        }
    }
}

// ---------------------------------------------------------------------------
// K3: fused nf + Ui/Uj.  grid (50, 2): node = x, m0 = 64y.
// ---------------------------------------------------------------------------
__global__ __launch_bounds__(256) void nfu_gemm(
    const unsigned short* __restrict__ h2h,
    const unsigned short* __restrict__ W3h,
    const float* __restrict__ b3,
    const unsigned short* __restrict__ E1ih,
    const unsigned short* __restrict__ E1jh,
    const float* __restrict__ Abc,
    float* __restrict__ outN,               // [128,3200] sigmoid
    unsigned short* __restrict__ Uih,       // [128*50,512]
    unsigned short* __restrict__ Ujh)
{
    __shared__ unsigned short Ah[3][2048];
    __shared__ unsigned short Bh[3][2048];
    __shared__ __align__(16) unsigned short nft[64][72];

    const int tid = threadIdx.x;
    const int lane = tid & 63;
    const int w = tid >> 6;
    const int ln = lane & 15;
    const int hi = lane >> 4;
    const int node = blockIdx.x;
    const int m0 = blockIdx.y * 64;

    const int srow = lane >> 2;
    const int scol = (lane & 3) * 8;
    const unsigned short* gA = h2h + (size_t)(m0 + 16 * w + srow) * 512 + scol;
    const unsigned short* gB = W3h + (size_t)(node * 64 + 16 * w + srow) * 512 + scol;
    unsigned short* lA = (unsigned short*)&Ah[0][0] + 512 * w;
    unsigned short* lB = (unsigned short*)&Bh[0][0] + 512 * w;

    f32x4 acc[4] = {};

    gll16(gA,      lA);          gll16(gB,      lB);
    gll16(gA + 32, lA + 2048);   gll16(gB + 32, lB + 2048);
    asm volatile("s_waitcnt vmcnt(2) lgkmcnt(0)\n\ts_barrier" ::: "memory");

    #pragma unroll
    for (int ks = 0; ks < 16; ++ks) {
        if (ks < 14) {
            const int bn = (ks + 2) % 3;
            gll16(gA + (ks + 2) * 32, lA + bn * 2048);
            gll16(gB + (ks + 2) * 32, lB + bn * 2048);
        }
        const int bb = ks % 3;
        f16x8 af = *(const f16x8*)&Ah[bb][(16 * w + ln) * 32 + hi * 8];
        f16x8 bf[4];
        #pragma unroll
        for (int ni = 0; ni < 4; ++ni)
            bf[ni] = *(const f16x8*)&Bh[bb][(16 * ni + ln) * 32 + hi * 8];
        #pragma unroll
        for (int ni = 0; ni < 4; ++ni)
            acc[ni] = __builtin_amdgcn_mfma_f32_16x16x32_f16(af, bf[ni], acc[ni], 0, 0, 0);
        if (ks < 14) {
            asm volatile("s_waitcnt vmcnt(2) lgkmcnt(0)\n\ts_barrier" ::: "memory");
        } else if (ks == 14) {
            asm volatile("s_waitcnt vmcnt(0) lgkmcnt(0)\n\ts_barrier" ::: "memory");
        }
    }

    #pragma unroll
    for (int ni = 0; ni < 4; ++ni) {
        int gnl = 16 * ni + ln;
        int gng = node * 64 + gnl;
        float bias = b3[gng];
        #pragma unroll
        for (int r = 0; r < 4; ++r) {
            int bl = 16 * w + 4 * hi + r;
            float v = acc[ni][r] + bias;
            outN[(size_t)(m0 + bl) * 3200 + gng] = sigmoidf_(v);
            nft[bl][gnl] = __builtin_bit_cast(unsigned short, (_Float16)v);
        }
    }
    __syncthreads();

    f16x8 af2[2][4];
    #pragma unroll
    for (int ks2 = 0; ks2 < 2; ++ks2)
        #pragma unroll
        for (int mi = 0; mi < 4; ++mi)
            af2[ks2][mi] = *(const f16x8*)&nft[16 * mi + ln][ks2 * 32 + hi * 8];

    #pragma unroll
    for (int ij = 0; ij < 2; ++ij) {
        const unsigned short* Ep = ij ? E1jh : E1ih;
        unsigned short* Ud = ij ? Ujh : Uih;
        #pragma unroll
        for (int half = 0; half < 2; ++half) {
            f32x4 acc2[4][4] = {};
            #pragma unroll
            for (int ks2 = 0; ks2 < 2; ++ks2) {
                f16x8 bf2[4];
                #pragma unroll
                for (int ni = 0; ni < 4; ++ni)
                    bf2[ni] = *(const f16x8*)(Ep +
                        (size_t)(128 * w + half * 64 + 16 * ni + ln) * 64 +
                        ks2 * 32 + hi * 8);
                #pragma unroll
                for (int ni = 0; ni < 4; ++ni)
                    #pragma unroll
                    for (int mi = 0; mi < 4; ++mi)
                        acc2[mi][ni] = __builtin_amdgcn_mfma_f32_16x16x32_f16(
                            af2[ks2][mi], bf2[ni], acc2[mi][ni], 0, 0, 0);
            }
            #pragma unroll
            for (int mi = 0; mi < 4; ++mi) {
                #pragma unroll
                for (int r = 0; r < 4; ++r) {
                    int batch = m0 + 16 * mi + 4 * hi + r;
                    #pragma unroll
                    for (int ni = 0; ni < 4; ++ni) {
                        int h = 128 * w + half * 64 + 16 * ni + ln;
                        float v = acc2[mi][ni][r];
                        if (ij == 0) v += Abc[(size_t)batch * 512 + h];
                        Ud[((size_t)batch * 50 + node) * 512 + h] =
                            __builtin_bit_cast(unsigned short, (_Float16)v);
                    }
                }
            }
        }
    }
}

// ---------------------------------------------------------------------------
// K4: MFMA edge kernel v10 — v9 + restored depth-2 bf register pipeline
// (bfA/bfB rename sets; bf(ks+1) issued BEFORE the MFMA(ks) cluster so the
// now-L2-resident load (XCD swizzle) is covered by ~233 cyc of MFMA issue).
// launch_bounds(256,3): unified regs ~136, no spill.
// Grid: 1D 4992 = 8 XCD x 624, bijective swizzle.
// ---------------------------------------------------------------------------
__global__ __launch_bounds__(256, 3) void edge_mfma(
    const unsigned short* __restrict__ Ui,   // [B*50,512] fp16 (incl. Abc)
    const unsigned short* __restrict__ Uj,   // [B*50,512] fp16
    const unsigned short* __restrict__ E2t,  // [64 kc][256 g][8] fp16
    const float* __restrict__ c2,
    const float* __restrict__ E3,
    const float* __restrict__ c3p,
    float* __restrict__ outE)                // [B,2450]
{
    __shared__ unsigned short As[2][PTILE * 32];   // 8KB dbuf, swizzled
    __shared__ float c2_s[256], e3_s[256];
    __shared__ int   ii_s[PTILE], jj_s[PTILE];
    __shared__ float red[PTILE][5];

    // XCD-bijective swizzle: 4992 = 8 * 624
    const int gid = blockIdx.x;
    const int nid = (gid & 7) * 624 + (gid >> 3);
    const int b   = nid / NTILES;
    const int p0  = (nid - b * NTILES) * PTILE;

    const int tid = threadIdx.x;
    const int lane = tid & 63;
    const int wid  = tid >> 6;    // g quarter
    const int ln = lane & 15;
    const int hi = lane >> 4;

    c2_s[tid] = c2[tid];
    e3_s[tid] = E3[tid];
    if (tid < PTILE) {
        int p = p0 + tid;
        int i = 0, j = 0;
        if (p < NPAIR) {
            i = p / 49;
            int kk = p - i * 49;
            j = kk + (kk >= i ? 1 : 0);
        }
        ii_s[tid] = i;
        jj_s[tid] = j;
    }
    __syncthreads();

    const unsigned short* UiB = Ui + (size_t)b * MAXN * HIDDEN;
    const unsigned short* UjB = Uj + (size_t)b * MAXN * HIDDEN;

    // A staging: thread -> (row srow, chunk sc) of 64x32 tile
    const int srow = tid >> 2;
    const int sc   = tid & 3;
    const unsigned short* gUi = UiB + (size_t)ii_s[srow] * HIDDEN + sc * 8;
    const unsigned short* gUj = UjB + (size_t)jj_s[srow] * HIDDEN + sc * 8;
    const int swr = srow * 32 + ((sc ^ ((srow >> 1) & 3)) * 8);

    // A fragment read (swizzled): af[mi] at ard + mi*16*32
    const int q   = hi ^ ((ln >> 1) & 3);
    const int ard = ln * 32 + q * 8;

    // B fragment global base: + ks*8192 + ni*128
    const unsigned short* bB = E2t + ((size_t)hi * 256 + 64 * wid + ln) * 8;

    f32x4 acc[4][4] = {};

    // ---- prologue: A(0)->LDS; U(1)->regs; bf(0)->bfA
    {
        f16x8 u0 = *(const f16x8*)gUi;
        f16x8 v0 = *(const f16x8*)gUj;
        *(f16x8*)&As[0][swr] = build_e1(u0, v0);
    }
    f16x8 uiN = *(const f16x8*)(gUi + 32);
    f16x8 ujN = *(const f16x8*)(gUj + 32);
    f16x8 bfA[4], bfB[4];
    #pragma unroll
    for (int ni = 0; ni < 4; ++ni)
        bfA[ni] = *(const f16x8*)(bB + ni * 128);
    asm volatile("s_waitcnt lgkmcnt(0)\n\ts_barrier" ::: "memory");

    #pragma unroll
    for (int ks = 0; ks < 16; ++ks) {
        // build + store A(ks+1) (consumes U(ks+1))
        if (ks < 15)
            *(f16x8*)&As[(ks + 1) & 1][swr] = build_e1(uiN, ujN);
        // prefetch U(ks+2)
        if (ks < 14) {
            uiN = *(const f16x8*)(gUi + 32 * (ks + 2));
            ujN = *(const f16x8*)(gUj + 32 * (ks + 2));
        }
        // af from LDS (post-barrier; 4 ds_read_b128)
        f16x8 af[4];
        #pragma unroll
        for (int mi = 0; mi < 4; ++mi)
            af[mi] = *(const f16x8*)&As[ks & 1][ard + mi * 512];
        // prefetch bf(ks+1) into the rename set BEFORE the MFMA cluster:
        // ~233 cyc of MFMA issue covers the L2-resident load.
        if (ks < 15) {
            #pragma unroll
            for (int ni = 0; ni < 4; ++ni) {
                f16x8 nb = *(const f16x8*)(bB + (size_t)(ks + 1) * 8192 + ni * 128);
                if (ks & 1) bfA[ni] = nb; else bfB[ni] = nb;
            }
        }
        __builtin_amdgcn_s_setprio(1);
        #pragma unroll
        for (int ni = 0; ni < 4; ++ni)
            #pragma unroll
            for (int mi = 0; mi < 4; ++mi)
                acc[mi][ni] = __builtin_amdgcn_mfma_f32_16x16x32_f16(
                    af[mi], (ks & 1) ? bfB[ni] : bfA[ni], acc[mi][ni], 0, 0, 0);
        __builtin_amdgcn_s_setprio(0);
        if (ks < 15)
            asm volatile("s_waitcnt lgkmcnt(0)\n\ts_barrier" ::: "memory");
    }

    // ---- epilogue
    const float c3v = c3p[0];
    #pragma unroll
    for (int mi = 0; mi < 4; ++mi) {
        #pragma unroll
        for (int r = 0; r < 4; ++r) {
            float part = 0.f;
            #pragma unroll
            for (int ni = 0; ni < 4; ++ni) {
                int g = 64 * wid + 16 * ni + ln;
                float v = fmaxf(acc[mi][ni][r] + c2_s[g], 0.f);
                part = fmaf(v, e3_s[g], part);
            }
            part += __shfl_xor(part, 1);
            part += __shfl_xor(part, 2);
            part += __shfl_xor(part, 4);
            part += __shfl_xor(part, 8);
            if (ln == 0) red[16 * mi + 4 * hi + r][wid] = part;
        }
    }
    __syncthreads();

    if (tid < PTILE) {
        int p = p0 + tid;
        if (p < NPAIR) {
            float s = red[tid][0] + red[tid][1] + red[tid][2] + red[tid][3] + c3v;
            outE[(size_t)b * NPAIR + p] = sigmoidf_(s);
        }
    }
}

// ---------------------------------------------------------------------------
extern "C" void kernel_launch(void* const* d_in, const int* in_sizes, int n_in,
                              void* d_out, int out_size, void* d_ws, size_t ws_size,
                              hipStream_t stream)
{
    const float* z  = (const float*)d_in[0];
    const float* W1 = (const float*)d_in[1];
    const float* b1 = (const float*)d_in[2];
    const float* W2 = (const float*)d_in[3];
    const float* b2 = (const float*)d_in[4];
    const float* W3 = (const float*)d_in[5];
    const float* b3 = (const float*)d_in[6];
    const float* E1 = (const float*)d_in[7];
    const float* c1 = (const float*)d_in[8];
    const float* E2 = (const float*)d_in[9];
    const float* c2 = (const float*)d_in[10];
    const float* E3 = (const float*)d_in[11];
    const float* c3 = (const float*)d_in[12];

    float* out = (float*)d_out;
    float* ws  = (float*)d_ws;

    // workspace layout
    float* Abc = ws;                                        // 65536 f32
    unsigned short* h1h  = (unsigned short*)(Abc + 65536);  // 65536
    unsigned short* h2h  = h1h + 65536;                     // 65536
    unsigned short* W2h  = h2h + 65536;                     // 262144
    unsigned short* W3h  = W2h + 262144;                    // 1638400
    unsigned short* E1ih = W3h + 1638400;                   // 32768
    unsigned short* E1jh = E1ih + 32768;                    // 32768
    unsigned short* E2t  = E1jh + 32768;                    // 131072
    unsigned short* Uih  = E2t + 131072;                    // 3276800
    unsigned short* Ujh  = Uih + 3276800;                   // 3276800

    dim3 blk(256);

    // K1: h1h, Abc, E2t, W2h, W3h, E1ih, E1jh
    prologue_a<<<dim3(528, 2), blk, 0, stream>>>(
        z, W1, b1, E1, c1, E2, W2, W3, E2t, W2h, W3h, E1ih, E1jh, h1h, Abc);

    // K2: h2h = relu(h1h@W2h^T + b2)
    h2_gemm<<<dim3(8, 2), blk, 0, stream>>>(h1h, W2h, b2, h2h);

    // K3: nf (sigmoid->out) + fused Ui/Uj
    nfu_gemm<<<dim3(50, 2), blk, 0, stream>>>(
        h2h, W3h, b3, E1ih, E1jh, Abc, out, Uih, Ujh);

    // K4: fused edge MLP (1D grid, XCD-swizzled)
    edge_mfma<<<dim3(NTILES * BATCH), blk, 0, stream>>>(
        Uih, Ujh, E2t, c2, E3, c3, out + BATCH * MAXN * NFD);
}

// Round 12
// 127.398 us; speedup vs baseline: 1.0581x; 1.0581x over previous
//
#include <hip/hip_runtime.h>
#include <hip/hip_bf16.h>
#include <math.h>

#define LATENT 256
#define HIDDEN 512
#define NFD    64
#define MAXN   50
#define BATCH  128
#define NPAIR  2450   // 50*49
#define PTILE  64
#define NTILES 39     // ceil(2450/64)

typedef __attribute__((ext_vector_type(8))) _Float16 f16x8;
typedef __attribute__((ext_vector_type(4))) float f32x4;
typedef __attribute__((ext_vector_type(4))) unsigned int u32x4;

__device__ __forceinline__ float sigmoidf_(float x) {
    return 1.0f / (1.0f + expf(-x));
}
__device__ __forceinline__ f16x8 build_e1(f16x8 ui, f16x8 uj) {
    f16x8 s = ui + uj;
    return __builtin_elementwise_max(s, (f16x8)(_Float16)0);
}
__device__ __forceinline__ void gll16(const void* g, void* l) {
    __builtin_amdgcn_global_load_lds(
        (const __attribute__((address_space(1))) void*)g,
        (__attribute__((address_space(3))) void*)l, 16, 0, 0);
}
__device__ __forceinline__ u32x4 pack8(float4 a, float4 b) {
    f16x8 h;
    h[0] = (_Float16)a.x; h[1] = (_Float16)a.y;
    h[2] = (_Float16)a.z; h[3] = (_Float16)a.w;
    h[4] = (_Float16)b.x; h[5] = (_Float16)b.y;
    h[6] = (_Float16)b.z; h[7] = (_Float16)b.w;
    return __builtin_bit_cast(u32x4, h);
}

// ---------------------------------------------------------------------------
// K1 prologue, grid (272, 4). Roles by blockIdx.x:
//  x<16     : fp32 gemm 32x64 tile (m0=32*y): h1h fp16 (n0<512) / Abc (n0>=512)
//  16<=x<32 : E2 -> E2t chunk-major fp16 (slot=(x-16)*4+y, 64 slots)
//  x>=32    : linear fp16 cvts W2h|W3h|E1ih|E1jh (slot=(x-32)*4+y, 960 slots)
// ---------------------------------------------------------------------------
__global__ __launch_bounds__(256) void prologue_a(
    const float* __restrict__ z,
    const float* __restrict__ W1, const float* __restrict__ b1,
    const float* __restrict__ E1, const float* __restrict__ c1,
    const float* __restrict__ E2, const float* __restrict__ W2,
    const float* __restrict__ W3,
    unsigned short* __restrict__ E2t,
    unsigned short* __restrict__ W2h,
    unsigned short* __restrict__ W3h,
    unsigned short* __restrict__ E1ih,
    unsigned short* __restrict__ E1jh,
    unsigned short* __restrict__ h1h, float* __restrict__ Abc)
{
    const int tid = threadIdx.x;

    if (blockIdx.x >= 32) {   // linear cvts
        int slot = (blockIdx.x - 32) * 4 + blockIdx.y;   // 0..959
        int e = (slot * 256 + tid) * 8;
        const float* src;
        unsigned short* dst;
        if (e < 262144) { src = W2 + e; dst = W2h + e; }
        else if (e < 1900544) { int l = e - 262144; src = W3 + l; dst = W3h + l; }
        else if (e < 1933312) {
            int l = e - 1900544; int row = l >> 6, col = l & 63;
            src = E1 + row * 384 + 256 + col; dst = E1ih + l;
        } else {
            int l = e - 1933312; int row = l >> 6, col = l & 63;
            src = E1 + row * 384 + 320 + col; dst = E1jh + l;
        }
        float4 a = *(const float4*)src;
        float4 b = *(const float4*)(src + 4);
        *(u32x4*)dst = pack8(a, b);
        return;
    }

    if (blockIdx.x >= 16) {   // E2 -> chunk-major fp16
        int idx = ((blockIdx.x - 16) * 4 + blockIdx.y) * 256 + tid;  // 16384
        int g  = idx & 255;
        int kc = idx >> 8;
        float4 a = *(const float4*)&E2[(size_t)g * 512 + kc * 8];
        float4 b = *(const float4*)&E2[(size_t)g * 512 + kc * 8 + 4];
        *(u32x4*)(E2t + (size_t)idx * 8) = pack8(a, b);
        return;
    }

    // fp32 NT gemm, 32x64 tile, 2x4/thread (R4-proven pattern)
    __shared__ __align__(16) float As[16][34];
    __shared__ __align__(16) float Bs[16][68];

    const int m0 = blockIdx.y * 32;
    const int n0 = blockIdx.x * 64;          // 0..1023
    const bool isE = n0 >= 512;
    const float* Bp = isE ? E1 + (size_t)(n0 - 512) * 384 : W1 + (size_t)n0 * 256;
    const int ldb = isE ? 384 : 256;

    const int sra = tid >> 3;        // 0..31
    const int kca = (tid & 7) * 2;
    const int srb = tid >> 2;        // 0..63
    const int kcb = (tid & 3) * 4;
    const int tx = tid & 15;
    const int ty = tid >> 4;         // 0..15

    float acc[2][4] = {};

    for (int k0 = 0; k0 < 256; k0 += 16) {
        float2 a2 = *(const float2*)&z[(size_t)(m0 + sra) * 256 + k0 + kca];
        As[kca][sra] = a2.x; As[kca + 1][sra] = a2.y;
        float4 b4 = *(const float4*)&Bp[(size_t)srb * ldb + k0 + kcb];
        Bs[kcb + 0][srb] = b4.x; Bs[kcb + 1][srb] = b4.y;
        Bs[kcb + 2][srb] = b4.z; Bs[kcb + 3][srb] = b4.w;
        __syncthreads();
        #pragma unroll
        for (int k = 0; k < 16; ++k) {
            float av[2], bv[4];
            av[0] = As[k][ty * 2]; av[1] = As[k][ty * 2 + 1];
            *(float4*)bv = *(const float4*)&Bs[k][tx * 4];
            #pragma unroll
            for (int r = 0; r < 2; ++r)
                #pragma unroll
                for (int c = 0; c < 4; ++c)
                    acc[r][c] = fmaf(av[r], bv[c], acc[r][c]);
        }
        __syncthreads();
    }

    #pragma unroll
    for (int r = 0; r < 2; ++r) {
        int gm = m0 + ty * 2 + r;
        #pragma unroll
        for (int c = 0; c < 4; ++c) {
            int gn = n0 + tx * 4 + c;
            if (isE) {
                int gl = gn - 512;
                Abc[(size_t)gm * 512 + gl] = acc[r][c] + c1[gl];
            } else {
                float v = fmaxf(acc[r][c] + b1[gn], 0.f);
                h1h[(size_t)gm * 512 + gn] =
                    __builtin_bit_cast(unsigned short, (_Float16)v);
            }
        }
    }
}

// ---------------------------------------------------------------------------
// K2: h2h = relu(h1h @ W2h^T + b2), fp16 MFMA. grid (8,2): n0=64x, m0=64y.
// ---------------------------------------------------------------------------
__global__ __launch_bounds__(256) void h2_gemm(
    const unsigned short* __restrict__ h1h,
    const unsigned short* __restrict__ W2h,
    const float* __restrict__ b2,
    unsigned short* __restrict__ h2h)
{
    __shared__ unsigned short Ah[3][2048];   // 64x32 fp16 per buf
    __shared__ unsigned short Bh[3][2048];

    const int tid = threadIdx.x;
    const int lane = tid & 63;
    const int w = tid >> 6;
    const int ln = lane & 15;
    const int hi = lane >> 4;
    const int m0 = blockIdx.y * 64;
    const int n0 = blockIdx.x * 64;

    const int srow = lane >> 2;             // 0..15 row within wave's 16
    const int scol = (lane & 3) * 8;
    const unsigned short* gA = h1h + (size_t)(m0 + 16 * w + srow) * 512 + scol;
    const unsigned short* gB = W2h + (size_t)(n0 + 16 * w + srow) * 512 + scol;
    unsigned short* lA = (unsigned short*)&Ah[0][0] + 512 * w;   // + buf*2048
    unsigned short* lB = (unsigned short*)&Bh[0][0] + 512 * w;

    f32x4 acc[4] = {};

    gll16(gA,      lA);          gll16(gB,      lB);
    gll16(gA + 32, lA + 2048);   gll16(gB + 32, lB + 2048);
    asm volatile("s_waitcnt vmcnt(2) lgkmcnt(0)\n\ts_barrier" ::: "memory");

    #pragma unroll
    for (int ks = 0; ks < 16; ++ks) {
        if (ks < 14) {
            const int bn = (ks + 2) % 3;
            gll16(gA + (ks + 2) * 32, lA + bn * 2048);
            gll16(gB + (ks + 2) * 32, lB + bn * 2048);
        }
        const int bb = ks % 3;
        f16x8 af = *(const f16x8*)&Ah[bb][(16 * w + ln) * 32 + hi * 8];
        f16x8 bf[4];
        #pragma unroll
        for (int ni = 0; ni < 4; ++ni)
            bf[ni] = *(const f16x8*)&Bh[bb][(16 * ni + ln) * 32 + hi * 8];
        #pragma unroll
        for (int ni = 0; ni < 4; ++ni)
            acc[ni] = __builtin_amdgcn_mfma_f32_16x16x32_f16(af, bf[ni], acc[ni], 0, 0, 0);
        if (ks < 14) {
            asm volatile("s_waitcnt vmcnt(2) lgkmcnt(0)\n\ts_barrier" ::: "memory");
        } else if (ks == 14) {
            asm volatile("s_waitcnt vmcnt(0) lgkmcnt(0)\n\ts_barrier" ::: "memory");
        }
    }

    #pragma unroll
    for (int ni = 0; ni < 4; ++ni) {
        int gn = n0 + 16 * ni + ln;
        float bias = b2[gn];
        #pragma unroll
        for (int r = 0; r < 4; ++r) {
            int gm = m0 + 16 * w + 4 * hi + r;
            float v = fmaxf(acc[ni][r] + bias, 0.f);
            h2h[(size_t)gm * 512 + gn] =
                __builtin_bit_cast(unsigned short, (_Float16)v);
        }
    }
}

// ---------------------------------------------------------------------------
// K3: fused nf + Ui/Uj.  grid (50, 2): node = x, m0 = 64y.
// ---------------------------------------------------------------------------
__global__ __launch_bounds__(256) void nfu_gemm(
    const unsigned short* __restrict__ h2h,
    const unsigned short* __restrict__ W3h,
    const float* __restrict__ b3,
    const unsigned short* __restrict__ E1ih,
    const unsigned short* __restrict__ E1jh,
    const float* __restrict__ Abc,
    float* __restrict__ outN,               // [128,3200] sigmoid
    unsigned short* __restrict__ Uih,       // [128*50,512]
    unsigned short* __restrict__ Ujh)
{
    __shared__ unsigned short Ah[3][2048];
    __shared__ unsigned short Bh[3][2048];
    __shared__ __align__(16) unsigned short nft[64][72];

    const int tid = threadIdx.x;
    const int lane = tid & 63;
    const int w = tid >> 6;
    const int ln = lane & 15;
    const int hi = lane >> 4;
    const int node = blockIdx.x;
    const int m0 = blockIdx.y * 64;

    const int srow = lane >> 2;
    const int scol = (lane & 3) * 8;
    const unsigned short* gA = h2h + (size_t)(m0 + 16 * w + srow) * 512 + scol;
    const unsigned short* gB = W3h + (size_t)(node * 64 + 16 * w + srow) * 512 + scol;
    unsigned short* lA = (unsigned short*)&Ah[0][0] + 512 * w;
    unsigned short* lB = (unsigned short*)&Bh[0][0] + 512 * w;

    f32x4 acc[4] = {};

    gll16(gA,      lA);          gll16(gB,      lB);
    gll16(gA + 32, lA + 2048);   gll16(gB + 32, lB + 2048);
    asm volatile("s_waitcnt vmcnt(2) lgkmcnt(0)\n\ts_barrier" ::: "memory");

    #pragma unroll
    for (int ks = 0; ks < 16; ++ks) {
        if (ks < 14) {
            const int bn = (ks + 2) % 3;
            gll16(gA + (ks + 2) * 32, lA + bn * 2048);
            gll16(gB + (ks + 2) * 32, lB + bn * 2048);
        }
        const int bb = ks % 3;
        f16x8 af = *(const f16x8*)&Ah[bb][(16 * w + ln) * 32 + hi * 8];
        f16x8 bf[4];
        #pragma unroll
        for (int ni = 0; ni < 4; ++ni)
            bf[ni] = *(const f16x8*)&Bh[bb][(16 * ni + ln) * 32 + hi * 8];
        #pragma unroll
        for (int ni = 0; ni < 4; ++ni)
            acc[ni] = __builtin_amdgcn_mfma_f32_16x16x32_f16(af, bf[ni], acc[ni], 0, 0, 0);
        if (ks < 14) {
            asm volatile("s_waitcnt vmcnt(2) lgkmcnt(0)\n\ts_barrier" ::: "memory");
        } else if (ks == 14) {
            asm volatile("s_waitcnt vmcnt(0) lgkmcnt(0)\n\ts_barrier" ::: "memory");
        }
    }

    #pragma unroll
    for (int ni = 0; ni < 4; ++ni) {
        int gnl = 16 * ni + ln;
        int gng = node * 64 + gnl;
        float bias = b3[gng];
        #pragma unroll
        for (int r = 0; r < 4; ++r) {
            int bl = 16 * w + 4 * hi + r;
            float v = acc[ni][r] + bias;
            outN[(size_t)(m0 + bl) * 3200 + gng] = sigmoidf_(v);
            nft[bl][gnl] = __builtin_bit_cast(unsigned short, (_Float16)v);
        }
    }
    __syncthreads();

    f16x8 af2[2][4];
    #pragma unroll
    for (int ks2 = 0; ks2 < 2; ++ks2)
        #pragma unroll
        for (int mi = 0; mi < 4; ++mi)
            af2[ks2][mi] = *(const f16x8*)&nft[16 * mi + ln][ks2 * 32 + hi * 8];

    #pragma unroll
    for (int ij = 0; ij < 2; ++ij) {
        const unsigned short* Ep = ij ? E1jh : E1ih;
        unsigned short* Ud = ij ? Ujh : Uih;
        #pragma unroll
        for (int half = 0; half < 2; ++half) {
            f32x4 acc2[4][4] = {};
            #pragma unroll
            for (int ks2 = 0; ks2 < 2; ++ks2) {
                f16x8 bf2[4];
                #pragma unroll
                for (int ni = 0; ni < 4; ++ni)
                    bf2[ni] = *(const f16x8*)(Ep +
                        (size_t)(128 * w + half * 64 + 16 * ni + ln) * 64 +
                        ks2 * 32 + hi * 8);
                #pragma unroll
                for (int ni = 0; ni < 4; ++ni)
                    #pragma unroll
                    for (int mi = 0; mi < 4; ++mi)
                        acc2[mi][ni] = __builtin_amdgcn_mfma_f32_16x16x32_f16(
                            af2[ks2][mi], bf2[ni], acc2[mi][ni], 0, 0, 0);
            }
            #pragma unroll
            for (int mi = 0; mi < 4; ++mi) {
                #pragma unroll
                for (int r = 0; r < 4; ++r) {
                    int batch = m0 + 16 * mi + 4 * hi + r;
                    #pragma unroll
                    for (int ni = 0; ni < 4; ++ni) {
                        int h = 128 * w + half * 64 + 16 * ni + ln;
                        float v = acc2[mi][ni][r];
                        if (ij == 0) v += Abc[(size_t)batch * 512 + h];
                        Ud[((size_t)batch * 50 + node) * 512 + h] =
                            __builtin_bit_cast(unsigned short, (_Float16)v);
                    }
                }
            }
        }
    }
}

// ---------------------------------------------------------------------------
// K4: MFMA edge kernel (R10 exact revert — best measured, 86 µs).
// Single bf register set (VGPR 64 arch + 64 acc), launch_bounds(256,4);
// B direct-from-global (chunk-major E2t), A dbuf LDS (swizzled);
// XCD-bijective 1D swizzle (4992 = 8 x 624).
// ---------------------------------------------------------------------------
__global__ __launch_bounds__(256, 4) void edge_mfma(
    const unsigned short* __restrict__ Ui,   // [B*50,512] fp16 (incl. Abc)
    const unsigned short* __restrict__ Uj,   // [B*50,512] fp16
    const unsigned short* __restrict__ E2t,  // [64 kc][256 g][8] fp16
    const float* __restrict__ c2,
    const float* __restrict__ E3,
    const float* __restrict__ c3p,
    float* __restrict__ outE)                // [B,2450]
{
    __shared__ unsigned short As[2][PTILE * 32];   // 8KB dbuf, swizzled
    __shared__ float c2_s[256], e3_s[256];
    __shared__ int   ii_s[PTILE], jj_s[PTILE];
    __shared__ float red[PTILE][5];

    // XCD-bijective swizzle: 4992 = 8 * 624
    const int gid = blockIdx.x;
    const int nid = (gid & 7) * 624 + (gid >> 3);
    const int b   = nid / NTILES;
    const int p0  = (nid - b * NTILES) * PTILE;

    const int tid = threadIdx.x;
    const int lane = tid & 63;
    const int wid  = tid >> 6;    // g quarter
    const int ln = lane & 15;
    const int hi = lane >> 4;

    c2_s[tid] = c2[tid];
    e3_s[tid] = E3[tid];
    if (tid < PTILE) {
        int p = p0 + tid;
        int i = 0, j = 0;
        if (p < NPAIR) {
            i = p / 49;
            int kk = p - i * 49;
            j = kk + (kk >= i ? 1 : 0);
        }
        ii_s[tid] = i;
        jj_s[tid] = j;
    }
    __syncthreads();

    const unsigned short* UiB = Ui + (size_t)b * MAXN * HIDDEN;
    const unsigned short* UjB = Uj + (size_t)b * MAXN * HIDDEN;

    // A staging: thread -> (row srow, chunk sc) of 64x32 tile
    const int srow = tid >> 2;
    const int sc   = tid & 3;
    const unsigned short* gUi = UiB + (size_t)ii_s[srow] * HIDDEN + sc * 8;
    const unsigned short* gUj = UjB + (size_t)jj_s[srow] * HIDDEN + sc * 8;
    const int swr = srow * 32 + ((sc ^ ((srow >> 1) & 3)) * 8);

    // A fragment read (swizzled): af[mi] at ard + mi*16*32
    const int q   = hi ^ ((ln >> 1) & 3);
    const int ard = ln * 32 + q * 8;

    // B fragment global base: + ks*8192 + ni*128
    const unsigned short* bB = E2t + ((size_t)hi * 256 + 64 * wid + ln) * 8;

    f32x4 acc[4][4] = {};

    // ---- prologue: A(0)->LDS; U(1)->regs; bf(0)->regs
    {
        f16x8 u0 = *(const f16x8*)gUi;
        f16x8 v0 = *(const f16x8*)gUj;
        *(f16x8*)&As[0][swr] = build_e1(u0, v0);
    }
    f16x8 uiN = *(const f16x8*)(gUi + 32);
    f16x8 ujN = *(const f16x8*)(gUj + 32);
    f16x8 bf[4];
    #pragma unroll
    for (int ni = 0; ni < 4; ++ni)
        bf[ni] = *(const f16x8*)(bB + ni * 128);
    asm volatile("s_waitcnt lgkmcnt(0)\n\ts_barrier" ::: "memory");

    #pragma unroll
    for (int ks = 0; ks < 16; ++ks) {
        // build + store A(ks+1) (consumes U(ks+1))
        if (ks < 15)
            *(f16x8*)&As[(ks + 1) & 1][swr] = build_e1(uiN, ujN);
        // prefetch U(ks+2)
        if (ks < 14) {
            uiN = *(const f16x8*)(gUi + 32 * (ks + 2));
            ujN = *(const f16x8*)(gUj + 32 * (ks + 2));
        }
        // af from LDS (post-barrier; 4 ds_read_b128)
        f16x8 af[4];
        #pragma unroll
        for (int mi = 0; mi < 4; ++mi)
            af[mi] = *(const f16x8*)&As[ks & 1][ard + mi * 512];
        // MFMA cluster (consumes bf(ks))
        __builtin_amdgcn_s_setprio(1);
        #pragma unroll
        for (int ni = 0; ni < 4; ++ni)
            #pragma unroll
            for (int mi = 0; mi < 4; ++mi)
                acc[mi][ni] = __builtin_amdgcn_mfma_f32_16x16x32_f16(
                    af[mi], bf[ni], acc[mi][ni], 0, 0, 0);
        __builtin_amdgcn_s_setprio(0);
        // reload bf for ks+1 (single set; issued after last MFMA read)
        if (ks < 15) {
            #pragma unroll
            for (int ni = 0; ni < 4; ++ni)
                bf[ni] = *(const f16x8*)(bB + (size_t)(ks + 1) * 8192 + ni * 128);
            asm volatile("s_waitcnt lgkmcnt(0)\n\ts_barrier" ::: "memory");
        }
    }

    // ---- epilogue
    const float c3v = c3p[0];
    #pragma unroll
    for (int mi = 0; mi < 4; ++mi) {
        #pragma unroll
        for (int r = 0; r < 4; ++r) {
            float part = 0.f;
            #pragma unroll
            for (int ni = 0; ni < 4; ++ni) {
                int g = 64 * wid + 16 * ni + ln;
                float v = fmaxf(acc[mi][ni][r] + c2_s[g], 0.f);
                part = fmaf(v, e3_s[g], part);
            }
            part += __shfl_xor(part, 1);
            part += __shfl_xor(part, 2);
            part += __shfl_xor(part, 4);
            part += __shfl_xor(part, 8);
            if (ln == 0) red[16 * mi + 4 * hi + r][wid] = part;
        }
    }
    __syncthreads();

    if (tid < PTILE) {
        int p = p0 + tid;
        if (p < NPAIR) {
            float s = red[tid][0] + red[tid][1] + red[tid][2] + red[tid][3] + c3v;
            outE[(size_t)b * NPAIR + p] = sigmoidf_(s);
        }
    }
}

// ---------------------------------------------------------------------------
extern "C" void kernel_launch(void* const* d_in, const int* in_sizes, int n_in,
                              void* d_out, int out_size, void* d_ws, size_t ws_size,
                              hipStream_t stream)
{
    const float* z  = (const float*)d_in[0];
    const float* W1 = (const float*)d_in[1];
    const float* b1 = (const float*)d_in[2];
    const float* W2 = (const float*)d_in[3];
    const float* b2 = (const float*)d_in[4];
    const float* W3 = (const float*)d_in[5];
    const float* b3 = (const float*)d_in[6];
    const float* E1 = (const float*)d_in[7];
    const float* c1 = (const float*)d_in[8];
    const float* E2 = (const float*)d_in[9];
    const float* c2 = (const float*)d_in[10];
    const float* E3 = (const float*)d_in[11];
    const float* c3 = (const float*)d_in[12];

    float* out = (float*)d_out;
    float* ws  = (float*)d_ws;

    // workspace layout
    float* Abc = ws;                                        // 65536 f32
    unsigned short* h1h  = (unsigned short*)(Abc + 65536);  // 65536
    unsigned short* h2h  = h1h + 65536;                     // 65536
    unsigned short* W2h  = h2h + 65536;                     // 262144
    unsigned short* W3h  = W2h + 262144;                    // 1638400
    unsigned short* E1ih = W3h + 1638400;                   // 32768
    unsigned short* E1jh = E1ih + 32768;                    // 32768
    unsigned short* E2t  = E1jh + 32768;                    // 131072
    unsigned short* Uih  = E2t + 131072;                    // 3276800
    unsigned short* Ujh  = Uih + 3276800;                   // 3276800

    dim3 blk(256);

    // K1: h1h, Abc, E2t, W2h, W3h, E1ih, E1jh
    prologue_a<<<dim3(272, 4), blk, 0, stream>>>(
        z, W1, b1, E1, c1, E2, W2, W3, E2t, W2h, W3h, E1ih, E1jh, h1h, Abc);

    // K2: h2h = relu(h1h@W2h^T + b2)
    h2_gemm<<<dim3(8, 2), blk, 0, stream>>>(h1h, W2h, b2, h2h);

    // K3: nf (sigmoid->out) + fused Ui/Uj
    nfu_gemm<<<dim3(50, 2), blk, 0, stream>>>(
        h2h, W3h, b3, E1ih, E1jh, Abc, out, Uih, Ujh);

    // K4: fused edge MLP (1D grid, XCD-swizzled)
    edge_mfma<<<dim3(NTILES * BATCH), blk, 0, stream>>>(
        Uih, Ujh, E2t, c2, E3, c3, out + BATCH * MAXN * NFD);
}

// Round 13
// 125.401 us; speedup vs baseline: 1.0750x; 1.0159x over previous
//
#include <hip/hip_runtime.h>
#include <hip/hip_bf16.h>
#include <math.h>

#define LATENT 256
#define HIDDEN 512
#define NFD    64
#define MAXN   50
#define BATCH  128
#define NPAIR  2450   // 50*49
#define PTILE  128
#define NTILES 20     // ceil(2450/128)

typedef __attribute__((ext_vector_type(8))) _Float16 f16x8;
typedef __attribute__((ext_vector_type(4))) float f32x4;
typedef __attribute__((ext_vector_type(4))) unsigned int u32x4;

__device__ __forceinline__ float sigmoidf_(float x) {
    return 1.0f / (1.0f + expf(-x));
}
__device__ __forceinline__ f16x8 build_e1(f16x8 ui, f16x8 uj) {
    f16x8 s = ui + uj;
    return __builtin_elementwise_max(s, (f16x8)(_Float16)0);
}
__device__ __forceinline__ void gll16(const void* g, void* l) {
    __builtin_amdgcn_global_load_lds(
        (const __attribute__((address_space(1))) void*)g,
        (__attribute__((address_space(3))) void*)l, 16, 0, 0);
}
__device__ __forceinline__ u32x4 pack8(float4 a, float4 b) {
    f16x8 h;
    h[0] = (_Float16)a.x; h[1] = (_Float16)a.y;
    h[2] = (_Float16)a.z; h[3] = (_Float16)a.w;
    h[4] = (_Float16)b.x; h[5] = (_Float16)b.y;
    h[6] = (_Float16)b.z; h[7] = (_Float16)b.w;
    return __builtin_bit_cast(u32x4, h);
}

// ---------------------------------------------------------------------------
// K1 prologue, grid (272, 4). Roles by blockIdx.x:
//  x<16     : fp32 gemm 32x64 tile (m0=32*y): h1h fp16 (n0<512) / Abc (n0>=512)
//  16<=x<32 : E2 -> E2t chunk-major fp16 (slot=(x-16)*4+y, 64 slots)
//  x>=32    : linear fp16 cvts W2h|W3h|E1ih|E1jh (slot=(x-32)*4+y, 960 slots)
// ---------------------------------------------------------------------------
__global__ __launch_bounds__(256) void prologue_a(
    const float* __restrict__ z,
    const float* __restrict__ W1, const float* __restrict__ b1,
    const float* __restrict__ E1, const float* __restrict__ c1,
    const float* __restrict__ E2, const float* __restrict__ W2,
    const float* __restrict__ W3,
    unsigned short* __restrict__ E2t,
    unsigned short* __restrict__ W2h,
    unsigned short* __restrict__ W3h,
    unsigned short* __restrict__ E1ih,
    unsigned short* __restrict__ E1jh,
    unsigned short* __restrict__ h1h, float* __restrict__ Abc)
{
    const int tid = threadIdx.x;

    if (blockIdx.x >= 32) {   // linear cvts
        int slot = (blockIdx.x - 32) * 4 + blockIdx.y;   // 0..959
        int e = (slot * 256 + tid) * 8;
        const float* src;
        unsigned short* dst;
        if (e < 262144) { src = W2 + e; dst = W2h + e; }
        else if (e < 1900544) { int l = e - 262144; src = W3 + l; dst = W3h + l; }
        else if (e < 1933312) {
            int l = e - 1900544; int row = l >> 6, col = l & 63;
            src = E1 + row * 384 + 256 + col; dst = E1ih + l;
        } else {
            int l = e - 1933312; int row = l >> 6, col = l & 63;
            src = E1 + row * 384 + 320 + col; dst = E1jh + l;
        }
        float4 a = *(const float4*)src;
        float4 b = *(const float4*)(src + 4);
        *(u32x4*)dst = pack8(a, b);
        return;
    }

    if (blockIdx.x >= 16) {   // E2 -> chunk-major fp16
        int idx = ((blockIdx.x - 16) * 4 + blockIdx.y) * 256 + tid;  // 16384
        int g  = idx & 255;
        int kc = idx >> 8;
        float4 a = *(const float4*)&E2[(size_t)g * 512 + kc * 8];
        float4 b = *(const float4*)&E2[(size_t)g * 512 + kc * 8 + 4];
        *(u32x4*)(E2t + (size_t)idx * 8) = pack8(a, b);
        return;
    }

    // fp32 NT gemm, 32x64 tile, 2x4/thread
    __shared__ __align__(16) float As[16][34];
    __shared__ __align__(16) float Bs[16][68];

    const int m0 = blockIdx.y * 32;
    const int n0 = blockIdx.x * 64;          // 0..1023
    const bool isE = n0 >= 512;
    const float* Bp = isE ? E1 + (size_t)(n0 - 512) * 384 : W1 + (size_t)n0 * 256;
    const int ldb = isE ? 384 : 256;

    const int sra = tid >> 3;        // 0..31
    const int kca = (tid & 7) * 2;
    const int srb = tid >> 2;        // 0..63
    const int kcb = (tid & 3) * 4;
    const int tx = tid & 15;
    const int ty = tid >> 4;         // 0..15

    float acc[2][4] = {};

    for (int k0 = 0; k0 < 256; k0 += 16) {
        float2 a2 = *(const float2*)&z[(size_t)(m0 + sra) * 256 + k0 + kca];
        As[kca][sra] = a2.x; As[kca + 1][sra] = a2.y;
        float4 b4 = *(const float4*)&Bp[(size_t)srb * ldb + k0 + kcb];
        Bs[kcb + 0][srb] = b4.x; Bs[kcb + 1][srb] = b4.y;
        Bs[kcb + 2][srb] = b4.z; Bs[kcb + 3][srb] = b4.w;
        __syncthreads();
        #pragma unroll
        for (int k = 0; k < 16; ++k) {
            float av[2], bv[4];
            av[0] = As[k][ty * 2]; av[1] = As[k][ty * 2 + 1];
            *(float4*)bv = *(const float4*)&Bs[k][tx * 4];
            #pragma unroll
            for (int r = 0; r < 2; ++r)
                #pragma unroll
                for (int c = 0; c < 4; ++c)
                    acc[r][c] = fmaf(av[r], bv[c], acc[r][c]);
        }
        __syncthreads();
    }

    #pragma unroll
    for (int r = 0; r < 2; ++r) {
        int gm = m0 + ty * 2 + r;
        #pragma unroll
        for (int c = 0; c < 4; ++c) {
            int gn = n0 + tx * 4 + c;
            if (isE) {
                int gl = gn - 512;
                Abc[(size_t)gm * 512 + gl] = acc[r][c] + c1[gl];
            } else {
                float v = fmaxf(acc[r][c] + b1[gn], 0.f);
                h1h[(size_t)gm * 512 + gn] =
                    __builtin_bit_cast(unsigned short, (_Float16)v);
            }
        }
    }
}

// ---------------------------------------------------------------------------
// K2: h2h = relu(h1h @ W2h^T + b2), fp16 MFMA. grid (8,2): n0=64x, m0=64y.
// ---------------------------------------------------------------------------
__global__ __launch_bounds__(256) void h2_gemm(
    const unsigned short* __restrict__ h1h,
    const unsigned short* __restrict__ W2h,
    const float* __restrict__ b2,
    unsigned short* __restrict__ h2h)
{
    __shared__ unsigned short Ah[3][2048];   // 64x32 fp16 per buf
    __shared__ unsigned short Bh[3][2048];

    const int tid = threadIdx.x;
    const int lane = tid & 63;
    const int w = tid >> 6;
    const int ln = lane & 15;
    const int hi = lane >> 4;
    const int m0 = blockIdx.y * 64;
    const int n0 = blockIdx.x * 64;

    const int srow = lane >> 2;             // 0..15 row within wave's 16
    const int scol = (lane & 3) * 8;
    const unsigned short* gA = h1h + (size_t)(m0 + 16 * w + srow) * 512 + scol;
    const unsigned short* gB = W2h + (size_t)(n0 + 16 * w + srow) * 512 + scol;
    unsigned short* lA = (unsigned short*)&Ah[0][0] + 512 * w;   // + buf*2048
    unsigned short* lB = (unsigned short*)&Bh[0][0] + 512 * w;

    f32x4 acc[4] = {};

    gll16(gA,      lA);          gll16(gB,      lB);
    gll16(gA + 32, lA + 2048);   gll16(gB + 32, lB + 2048);
    asm volatile("s_waitcnt vmcnt(2) lgkmcnt(0)\n\ts_barrier" ::: "memory");

    #pragma unroll
    for (int ks = 0; ks < 16; ++ks) {
        if (ks < 14) {
            const int bn = (ks + 2) % 3;
            gll16(gA + (ks + 2) * 32, lA + bn * 2048);
            gll16(gB + (ks + 2) * 32, lB + bn * 2048);
        }
        const int bb = ks % 3;
        f16x8 af = *(const f16x8*)&Ah[bb][(16 * w + ln) * 32 + hi * 8];
        f16x8 bf[4];
        #pragma unroll
        for (int ni = 0; ni < 4; ++ni)
            bf[ni] = *(const f16x8*)&Bh[bb][(16 * ni + ln) * 32 + hi * 8];
        #pragma unroll
        for (int ni = 0; ni < 4; ++ni)
            acc[ni] = __builtin_amdgcn_mfma_f32_16x16x32_f16(af, bf[ni], acc[ni], 0, 0, 0);
        if (ks < 14) {
            asm volatile("s_waitcnt vmcnt(2) lgkmcnt(0)\n\ts_barrier" ::: "memory");
        } else if (ks == 14) {
            asm volatile("s_waitcnt vmcnt(0) lgkmcnt(0)\n\ts_barrier" ::: "memory");
        }
    }

    #pragma unroll
    for (int ni = 0; ni < 4; ++ni) {
        int gn = n0 + 16 * ni + ln;
        float bias = b2[gn];
        #pragma unroll
        for (int r = 0; r < 4; ++r) {
            int gm = m0 + 16 * w + 4 * hi + r;
            float v = fmaxf(acc[ni][r] + bias, 0.f);
            h2h[(size_t)gm * 512 + gn] =
                __builtin_bit_cast(unsigned short, (_Float16)v);
        }
    }
}

// ---------------------------------------------------------------------------
// K3: fused nf + Ui/Uj.  grid (50, 2): node = x, m0 = 64y.
// ---------------------------------------------------------------------------
__global__ __launch_bounds__(256) void nfu_gemm(
    const unsigned short* __restrict__ h2h,
    const unsigned short* __restrict__ W3h,
    const float* __restrict__ b3,
    const unsigned short* __restrict__ E1ih,
    const unsigned short* __restrict__ E1jh,
    const float* __restrict__ Abc,
    float* __restrict__ outN,               // [128,3200] sigmoid
    unsigned short* __restrict__ Uih,       // [128*50,512]
    unsigned short* __restrict__ Ujh)
{
    __shared__ unsigned short Ah[3][2048];
    __shared__ unsigned short Bh[3][2048];
    __shared__ __align__(16) unsigned short nft[64][72];

    const int tid = threadIdx.x;
    const int lane = tid & 63;
    const int w = tid >> 6;
    const int ln = lane & 15;
    const int hi = lane >> 4;
    const int node = blockIdx.x;
    const int m0 = blockIdx.y * 64;

    const int srow = lane >> 2;
    const int scol = (lane & 3) * 8;
    const unsigned short* gA = h2h + (size_t)(m0 + 16 * w + srow) * 512 + scol;
    const unsigned short* gB = W3h + (size_t)(node * 64 + 16 * w + srow) * 512 + scol;
    unsigned short* lA = (unsigned short*)&Ah[0][0] + 512 * w;
    unsigned short* lB = (unsigned short*)&Bh[0][0] + 512 * w;

    f32x4 acc[4] = {};

    gll16(gA,      lA);          gll16(gB,      lB);
    gll16(gA + 32, lA + 2048);   gll16(gB + 32, lB + 2048);
    asm volatile("s_waitcnt vmcnt(2) lgkmcnt(0)\n\ts_barrier" ::: "memory");

    #pragma unroll
    for (int ks = 0; ks < 16; ++ks) {
        if (ks < 14) {
            const int bn = (ks + 2) % 3;
            gll16(gA + (ks + 2) * 32, lA + bn * 2048);
            gll16(gB + (ks + 2) * 32, lB + bn * 2048);
        }
        const int bb = ks % 3;
        f16x8 af = *(const f16x8*)&Ah[bb][(16 * w + ln) * 32 + hi * 8];
        f16x8 bf[4];
        #pragma unroll
        for (int ni = 0; ni < 4; ++ni)
            bf[ni] = *(const f16x8*)&Bh[bb][(16 * ni + ln) * 32 + hi * 8];
        #pragma unroll
        for (int ni = 0; ni < 4; ++ni)
            acc[ni] = __builtin_amdgcn_mfma_f32_16x16x32_f16(af, bf[ni], acc[ni], 0, 0, 0);
        if (ks < 14) {
            asm volatile("s_waitcnt vmcnt(2) lgkmcnt(0)\n\ts_barrier" ::: "memory");
        } else if (ks == 14) {
            asm volatile("s_waitcnt vmcnt(0) lgkmcnt(0)\n\ts_barrier" ::: "memory");
        }
    }

    #pragma unroll
    for (int ni = 0; ni < 4; ++ni) {
        int gnl = 16 * ni + ln;
        int gng = node * 64 + gnl;
        float bias = b3[gng];
        #pragma unroll
        for (int r = 0; r < 4; ++r) {
            int bl = 16 * w + 4 * hi + r;
            float v = acc[ni][r] + bias;
            outN[(size_t)(m0 + bl) * 3200 + gng] = sigmoidf_(v);
            nft[bl][gnl] = __builtin_bit_cast(unsigned short, (_Float16)v);
        }
    }
    __syncthreads();

    f16x8 af2[2][4];
    #pragma unroll
    for (int ks2 = 0; ks2 < 2; ++ks2)
        #pragma unroll
        for (int mi = 0; mi < 4; ++mi)
            af2[ks2][mi] = *(const f16x8*)&nft[16 * mi + ln][ks2 * 32 + hi * 8];

    #pragma unroll
    for (int ij = 0; ij < 2; ++ij) {
        const unsigned short* Ep = ij ? E1jh : E1ih;
        unsigned short* Ud = ij ? Ujh : Uih;
        #pragma unroll
        for (int half = 0; half < 2; ++half) {
            f32x4 acc2[4][4] = {};
            #pragma unroll
            for (int ks2 = 0; ks2 < 2; ++ks2) {
                f16x8 bf2[4];
                #pragma unroll
                for (int ni = 0; ni < 4; ++ni)
                    bf2[ni] = *(const f16x8*)(Ep +
                        (size_t)(128 * w + half * 64 + 16 * ni + ln) * 64 +
                        ks2 * 32 + hi * 8);
                #pragma unroll
                for (int ni = 0; ni < 4; ++ni)
                    #pragma unroll
                    for (int mi = 0; mi < 4; ++mi)
                        acc2[mi][ni] = __builtin_amdgcn_mfma_f32_16x16x32_f16(
                            af2[ks2][mi], bf2[ni], acc2[mi][ni], 0, 0, 0);
            }
            #pragma unroll
            for (int mi = 0; mi < 4; ++mi) {
                #pragma unroll
                for (int r = 0; r < 4; ++r) {
                    int batch = m0 + 16 * mi + 4 * hi + r;
                    #pragma unroll
                    for (int ni = 0; ni < 4; ++ni) {
                        int h = 128 * w + half * 64 + 16 * ni + ln;
                        float v = acc2[mi][ni][r];
                        if (ij == 0) v += Abc[(size_t)batch * 512 + h];
                        Ud[((size_t)batch * 50 + node) * 512 + h] =
                            __builtin_bit_cast(unsigned short, (_Float16)v);
                    }
                }
            }
        }
    }
}

// ---------------------------------------------------------------------------
// K4: MFMA edge kernel v11 — R10 per-wave recipe at PTILE=128 / 8 waves.
// Each E2t pass (256KB L2) now covers 128 pairs -> B L2 traffic halves
// (1.25GB -> 0.64GB); per-pair barrier count halves; 16 waves/CU
// (2 blocks x 8 waves, 128 unified VGPR) = 4 waves/SIMD.
// Waves: wr = wid>>2 (p half), wc = wid&3 (g quarter); wave tile 64x64.
// Grid: 1D 2560 = 8 XCD x 320, bijective swizzle.
// ---------------------------------------------------------------------------
__global__ __launch_bounds__(512, 2) void edge_mfma(
    const unsigned short* __restrict__ Ui,   // [B*50,512] fp16 (incl. Abc)
    const unsigned short* __restrict__ Uj,   // [B*50,512] fp16
    const unsigned short* __restrict__ E2t,  // [64 kc][256 g][8] fp16
    const float* __restrict__ c2,
    const float* __restrict__ E3,
    const float* __restrict__ c3p,
    float* __restrict__ outE)                // [B,2450]
{
    __shared__ unsigned short As[2][PTILE * 32];   // 16KB dbuf, swizzled
    __shared__ float c2_s[256], e3_s[256];
    __shared__ int   ii_s[PTILE], jj_s[PTILE];
    __shared__ float red[PTILE][5];

    // XCD-bijective swizzle: 2560 = 8 * 320
    const int gid = blockIdx.x;
    const int nid = (gid & 7) * 320 + (gid >> 3);
    const int b   = nid / NTILES;
    const int p0  = (nid - b * NTILES) * PTILE;

    const int tid = threadIdx.x;
    const int lane = tid & 63;
    const int wid  = tid >> 6;    // 0..7
    const int wr = wid >> 2;      // 0..1 : p half
    const int wc = wid & 3;       // 0..3 : g quarter
    const int ln = lane & 15;
    const int hi = lane >> 4;

    if (tid < 256) { c2_s[tid] = c2[tid]; e3_s[tid] = E3[tid]; }
    if (tid < PTILE) {
        int p = p0 + tid;
        int i = 0, j = 0;
        if (p < NPAIR) {
            i = p / 49;
            int kk = p - i * 49;
            j = kk + (kk >= i ? 1 : 0);
        }
        ii_s[tid] = i;
        jj_s[tid] = j;
    }
    __syncthreads();

    const unsigned short* UiB = Ui + (size_t)b * MAXN * HIDDEN;
    const unsigned short* UjB = Uj + (size_t)b * MAXN * HIDDEN;

    // A staging: thread -> (row tid>>2 of 128, chunk tid&3) of 128x32 tile
    const int srow = tid >> 2;
    const int sc   = tid & 3;
    const unsigned short* gUi = UiB + (size_t)ii_s[srow] * HIDDEN + sc * 8;
    const unsigned short* gUj = UjB + (size_t)jj_s[srow] * HIDDEN + sc * 8;
    const int swr = srow * 32 + ((sc ^ ((srow >> 1) & 3)) * 8);

    // A fragment read (swizzled): af[mi] at ard + mi*16*32
    const int q   = hi ^ ((ln >> 1) & 3);
    const int ard = (64 * wr + ln) * 32 + q * 8;

    // B fragment global base: + ks*8192 + ni*128
    const unsigned short* bB = E2t + ((size_t)hi * 256 + 64 * wc + ln) * 8;

    f32x4 acc[4][4] = {};

    // ---- prologue: A(0)->LDS; U(1)->regs; bf(0)->regs
    {
        f16x8 u0 = *(const f16x8*)gUi;
        f16x8 v0 = *(const f16x8*)gUj;
        *(f16x8*)&As[0][swr] = build_e1(u0, v0);
    }
    f16x8 uiN = *(const f16x8*)(gUi + 32);
    f16x8 ujN = *(const f16x8*)(gUj + 32);
    f16x8 bf[4];
    #pragma unroll
    for (int ni = 0; ni < 4; ++ni)
        bf[ni] = *(const f16x8*)(bB + ni * 128);
    asm volatile("s_waitcnt lgkmcnt(0)\n\ts_barrier" ::: "memory");

    #pragma unroll
    for (int ks = 0; ks < 16; ++ks) {
        // build + store A(ks+1) (consumes U(ks+1))
        if (ks < 15)
            *(f16x8*)&As[(ks + 1) & 1][swr] = build_e1(uiN, ujN);
        // prefetch U(ks+2)
        if (ks < 14) {
            uiN = *(const f16x8*)(gUi + 32 * (ks + 2));
            ujN = *(const f16x8*)(gUj + 32 * (ks + 2));
        }
        // af from LDS (post-barrier; 4 ds_read_b128)
        f16x8 af[4];
        #pragma unroll
        for (int mi = 0; mi < 4; ++mi)
            af[mi] = *(const f16x8*)&As[ks & 1][ard + mi * 512];
        // MFMA cluster (consumes bf(ks))
        __builtin_amdgcn_s_setprio(1);
        #pragma unroll
        for (int ni = 0; ni < 4; ++ni)
            #pragma unroll
            for (int mi = 0; mi < 4; ++mi)
                acc[mi][ni] = __builtin_amdgcn_mfma_f32_16x16x32_f16(
                    af[mi], bf[ni], acc[mi][ni], 0, 0, 0);
        __builtin_amdgcn_s_setprio(0);
        // reload bf for ks+1 (single set; issued after last MFMA read)
        if (ks < 15) {
            #pragma unroll
            for (int ni = 0; ni < 4; ++ni)
                bf[ni] = *(const f16x8*)(bB + (size_t)(ks + 1) * 8192 + ni * 128);
            asm volatile("s_waitcnt lgkmcnt(0)\n\ts_barrier" ::: "memory");
        }
    }

    // ---- epilogue
    const float c3v = c3p[0];
    #pragma unroll
    for (int mi = 0; mi < 4; ++mi) {
        #pragma unroll
        for (int r = 0; r < 4; ++r) {
            float part = 0.f;
            #pragma unroll
            for (int ni = 0; ni < 4; ++ni) {
                int g = 64 * wc + 16 * ni + ln;
                float v = fmaxf(acc[mi][ni][r] + c2_s[g], 0.f);
                part = fmaf(v, e3_s[g], part);
            }
            part += __shfl_xor(part, 1);
            part += __shfl_xor(part, 2);
            part += __shfl_xor(part, 4);
            part += __shfl_xor(part, 8);
            if (ln == 0) red[64 * wr + 16 * mi + 4 * hi + r][wc] = part;
        }
    }
    __syncthreads();

    if (tid < PTILE) {
        int p = p0 + tid;
        if (p < NPAIR) {
            float s = red[tid][0] + red[tid][1] + red[tid][2] + red[tid][3] + c3v;
            outE[(size_t)b * NPAIR + p] = sigmoidf_(s);
        }
    }
}

// ---------------------------------------------------------------------------
extern "C" void kernel_launch(void* const* d_in, const int* in_sizes, int n_in,
                              void* d_out, int out_size, void* d_ws, size_t ws_size,
                              hipStream_t stream)
{
    const float* z  = (const float*)d_in[0];
    const float* W1 = (const float*)d_in[1];
    const float* b1 = (const float*)d_in[2];
    const float* W2 = (const float*)d_in[3];
    const float* b2 = (const float*)d_in[4];
    const float* W3 = (const float*)d_in[5];
    const float* b3 = (const float*)d_in[6];
    const float* E1 = (const float*)d_in[7];
    const float* c1 = (const float*)d_in[8];
    const float* E2 = (const float*)d_in[9];
    const float* c2 = (const float*)d_in[10];
    const float* E3 = (const float*)d_in[11];
    const float* c3 = (const float*)d_in[12];

    float* out = (float*)d_out;
    float* ws  = (float*)d_ws;

    // workspace layout
    float* Abc = ws;                                        // 65536 f32
    unsigned short* h1h  = (unsigned short*)(Abc + 65536);  // 65536
    unsigned short* h2h  = h1h + 65536;                     // 65536
    unsigned short* W2h  = h2h + 65536;                     // 262144
    unsigned short* W3h  = W2h + 262144;                    // 1638400
    unsigned short* E1ih = W3h + 1638400;                   // 32768
    unsigned short* E1jh = E1ih + 32768;                    // 32768
    unsigned short* E2t  = E1jh + 32768;                    // 131072
    unsigned short* Uih  = E2t + 131072;                    // 3276800
    unsigned short* Ujh  = Uih + 3276800;                   // 3276800

    dim3 blk(256);

    // K1: h1h, Abc, E2t, W2h, W3h, E1ih, E1jh
    prologue_a<<<dim3(272, 4), blk, 0, stream>>>(
        z, W1, b1, E1, c1, E2, W2, W3, E2t, W2h, W3h, E1ih, E1jh, h1h, Abc);

    // K2: h2h = relu(h1h@W2h^T + b2)
    h2_gemm<<<dim3(8, 2), blk, 0, stream>>>(h1h, W2h, b2, h2h);

    // K3: nf (sigmoid->out) + fused Ui/Uj
    nfu_gemm<<<dim3(50, 2), blk, 0, stream>>>(
        h2h, W3h, b3, E1ih, E1jh, Abc, out, Uih, Ujh);

    // K4: fused edge MLP (1D grid 2560, XCD-swizzled, 512 thr)
    edge_mfma<<<dim3(NTILES * BATCH), dim3(512), 0, stream>>>(
        Uih, Ujh, E2t, c2, E3, c3, out + BATCH * MAXN * NFD);
}

// Round 14
// 124.657 us; speedup vs baseline: 1.0814x; 1.0060x over previous
//
#include <hip/hip_runtime.h>
#include <hip/hip_bf16.h>
#include <math.h>

#define LATENT 256
#define HIDDEN 512
#define NFD    64
#define MAXN   50
#define BATCH  128
#define NPAIR  2450   // 50*49
#define PTILE  64
#define NTILES 39     // ceil(2450/64)

typedef __attribute__((ext_vector_type(8))) _Float16 f16x8;
typedef __attribute__((ext_vector_type(4))) float f32x4;
typedef __attribute__((ext_vector_type(4))) unsigned int u32x4;

__device__ __forceinline__ float sigmoidf_(float x) {
    return 1.0f / (1.0f + expf(-x));
}
__device__ __forceinline__ f16x8 build_e1(f16x8 ui, f16x8 uj) {
    f16x8 s = ui + uj;
    return __builtin_elementwise_max(s, (f16x8)(_Float16)0);
}
__device__ __forceinline__ u32x4 pack8(float4 a, float4 b) {
    f16x8 h;
    h[0] = (_Float16)a.x; h[1] = (_Float16)a.y;
    h[2] = (_Float16)a.z; h[3] = (_Float16)a.w;
    h[4] = (_Float16)b.x; h[5] = (_Float16)b.y;
    h[6] = (_Float16)b.z; h[7] = (_Float16)b.w;
    return __builtin_bit_cast(u32x4, h);
}

// ---------------------------------------------------------------------------
// K1 prologue, grid (272, 4). Roles by blockIdx.x:
//  x<16     : fp32 gemm 32x64 tile (m0=32*y): h1h fp16 (n0<512) / Abc (n0>=512)
//  16<=x<32 : E2 -> E2t chunk-major fp16 [kc 0-63][256 g][8]
//  x>=32    : cvts: W2->W2t chunk-major [kc][512][8];
//             W3->W3t node-chunk-major [node][kc][64][8];
//             E1i/E1j -> linear [512 h][64 k] fp16
// ---------------------------------------------------------------------------
__global__ __launch_bounds__(256) void prologue_a(
    const float* __restrict__ z,
    const float* __restrict__ W1, const float* __restrict__ b1,
    const float* __restrict__ E1, const float* __restrict__ c1,
    const float* __restrict__ E2, const float* __restrict__ W2,
    const float* __restrict__ W3,
    unsigned short* __restrict__ E2t,
    unsigned short* __restrict__ W2t,
    unsigned short* __restrict__ W3t,
    unsigned short* __restrict__ E1ih,
    unsigned short* __restrict__ E1jh,
    unsigned short* __restrict__ h1h, float* __restrict__ Abc)
{
    const int tid = threadIdx.x;

    if (blockIdx.x >= 32) {   // conversions
        int slot = (blockIdx.x - 32) * 4 + blockIdx.y;   // 0..959
        int e = (slot * 256 + tid) * 8;
        float4 a, b;
        unsigned short* dst;
        if (e < 262144) {                 // W2 [512][512] -> W2t [kc][512][8]
            int row = e >> 9, k = e & 511;
            a = *(const float4*)&W2[e];
            b = *(const float4*)&W2[e + 4];
            dst = W2t + (((k >> 3) * 512 + row) << 3);
        } else if (e < 1900544) {         // W3 [3200][512] -> W3t [node][kc][64][8]
            int l = e - 262144;
            int grow = l >> 9, k = l & 511;
            int node = grow >> 6, row = grow & 63;
            a = *(const float4*)&W3[l];
            b = *(const float4*)&W3[l + 4];
            dst = W3t + node * 32768 + (((k >> 3) * 64 + row) << 3);
        } else if (e < 1933312) {         // E1i -> linear [512][64]
            int l = e - 1900544; int row = l >> 6, col = l & 63;
            a = *(const float4*)&E1[row * 384 + 256 + col];
            b = *(const float4*)&E1[row * 384 + 260 + col];
            dst = E1ih + l;
        } else {                          // E1j -> linear [512][64]
            int l = e - 1933312; int row = l >> 6, col = l & 63;
            a = *(const float4*)&E1[row * 384 + 320 + col];
            b = *(const float4*)&E1[row * 384 + 324 + col];
            dst = E1jh + l;
        }
        *(u32x4*)dst = pack8(a, b);
        return;
    }

    if (blockIdx.x >= 16) {   // E2 -> chunk-major fp16
        int idx = ((blockIdx.x - 16) * 4 + blockIdx.y) * 256 + tid;  // 16384
        int g  = idx & 255;
        int kc = idx >> 8;
        float4 a = *(const float4*)&E2[(size_t)g * 512 + kc * 8];
        float4 b = *(const float4*)&E2[(size_t)g * 512 + kc * 8 + 4];
        *(u32x4*)(E2t + (size_t)idx * 8) = pack8(a, b);
        return;
    }

    // fp32 NT gemm, 32x64 tile, 2x4/thread
    __shared__ __align__(16) float As[16][34];
    __shared__ __align__(16) float Bs[16][68];

    const int m0 = blockIdx.y * 32;
    const int n0 = blockIdx.x * 64;          // 0..1023
    const bool isE = n0 >= 512;
    const float* Bp = isE ? E1 + (size_t)(n0 - 512) * 384 : W1 + (size_t)n0 * 256;
    const int ldb = isE ? 384 : 256;

    const int sra = tid >> 3;        // 0..31
    const int kca = (tid & 7) * 2;
    const int srb = tid >> 2;        // 0..63
    const int kcb = (tid & 3) * 4;
    const int tx = tid & 15;
    const int ty = tid >> 4;         // 0..15

    float acc[2][4] = {};

    for (int k0 = 0; k0 < 256; k0 += 16) {
        float2 a2 = *(const float2*)&z[(size_t)(m0 + sra) * 256 + k0 + kca];
        As[kca][sra] = a2.x; As[kca + 1][sra] = a2.y;
        float4 b4 = *(const float4*)&Bp[(size_t)srb * ldb + k0 + kcb];
        Bs[kcb + 0][srb] = b4.x; Bs[kcb + 1][srb] = b4.y;
        Bs[kcb + 2][srb] = b4.z; Bs[kcb + 3][srb] = b4.w;
        __syncthreads();
        #pragma unroll
        for (int k = 0; k < 16; ++k) {
            float av[2], bv[4];
            av[0] = As[k][ty * 2]; av[1] = As[k][ty * 2 + 1];
            *(float4*)bv = *(const float4*)&Bs[k][tx * 4];
            #pragma unroll
            for (int r = 0; r < 2; ++r)
                #pragma unroll
                for (int c = 0; c < 4; ++c)
                    acc[r][c] = fmaf(av[r], bv[c], acc[r][c]);
        }
        __syncthreads();
    }

    #pragma unroll
    for (int r = 0; r < 2; ++r) {
        int gm = m0 + ty * 2 + r;
        #pragma unroll
        for (int c = 0; c < 4; ++c) {
            int gn = n0 + tx * 4 + c;
            if (isE) {
                int gl = gn - 512;
                Abc[(size_t)gm * 512 + gl] = acc[r][c] + c1[gl];
            } else {
                float v = fmaxf(acc[r][c] + b1[gn], 0.f);
                h1h[(size_t)gm * 512 + gn] =
                    __builtin_bit_cast(unsigned short, (_Float16)v);
            }
        }
    }
}

// ---------------------------------------------------------------------------
// K3': fused h2 + nf + Ui/Uj.  grid (50, 2): node = x, m0 = 64y. 512 thr.
//  Phase A (8 waves): h2s[64][512] = relu(h1h[m0-slice] @ W2t^T + b2) in LDS.
//    Wave w8 computes 64x64 subtile (cols 64*w8): A = h1h via reg-stage ->
//    swizzled LDS dbuf; B = W2t chunk-major direct-from-global (edge recipe).
//  Phase B (waves 0-3): nf tile = h2s @ W3t[node]^T + b3; sigmoid -> out,
//    fp16 -> nft. A-frags straight from h2s (no staging), B direct-global.
//  Phase C (waves 0-3): Ui/Uj from nft @ E1i/E1j (verbatim from R9-R13).
// ---------------------------------------------------------------------------
__global__ __launch_bounds__(512, 1) void nfu_gemm(
    const unsigned short* __restrict__ h1h,
    const unsigned short* __restrict__ W2t,   // [kc][512][8]
    const float* __restrict__ b2,
    const unsigned short* __restrict__ W3t,   // [node][kc][64][8]
    const float* __restrict__ b3,
    const unsigned short* __restrict__ E1ih,
    const unsigned short* __restrict__ E1jh,
    const float* __restrict__ Abc,
    float* __restrict__ outN,               // [128,3200] sigmoid
    unsigned short* __restrict__ Uih,       // [128*50,512]
    unsigned short* __restrict__ Ujh)
{
    __shared__ unsigned short As[2][64 * 32];          // 8KB h1 dbuf, swizzled
    __shared__ __align__(16) unsigned short h2s[64][520];  // 66.6KB
    __shared__ __align__(16) unsigned short nft[64][72];

    const int tid = threadIdx.x;
    const int lane = tid & 63;
    const int w8 = tid >> 6;     // 0..7
    const int w  = w8 & 3;       // phases B/C wave id
    const int ln = lane & 15;
    const int hi = lane >> 4;
    const int node = blockIdx.x;
    const int m0 = blockIdx.y * 64;

    // ---- phase A ----
    const int srow = (tid & 255) >> 2;
    const int sc   = tid & 3;
    const unsigned short* gA = h1h + (size_t)(m0 + srow) * 512 + sc * 8;
    const int swr = srow * 32 + ((sc ^ ((srow >> 1) & 3)) * 8);
    const int q   = hi ^ ((ln >> 1) & 3);
    const int ard = ln * 32 + q * 8;
    const unsigned short* bB = W2t + ((size_t)hi * 512 + 64 * w8 + ln) * 8;

    f32x4 acc[4][4] = {};
    f16x8 hN = {};
    if (tid < 256) {
        f16x8 h0 = *(const f16x8*)gA;
        *(f16x8*)&As[0][swr] = h0;
        hN = *(const f16x8*)(gA + 32);
    }
    f16x8 bf[4];
    #pragma unroll
    for (int ni = 0; ni < 4; ++ni)
        bf[ni] = *(const f16x8*)(bB + ni * 128);
    asm volatile("s_waitcnt lgkmcnt(0)\n\ts_barrier" ::: "memory");

    #pragma unroll
    for (int ks = 0; ks < 16; ++ks) {
        if (tid < 256 && ks < 15)
            *(f16x8*)&As[(ks + 1) & 1][swr] = hN;
        if (tid < 256 && ks < 14)
            hN = *(const f16x8*)(gA + 32 * (ks + 2));
        f16x8 af[4];
        #pragma unroll
        for (int mi = 0; mi < 4; ++mi)
            af[mi] = *(const f16x8*)&As[ks & 1][ard + mi * 512];
        __builtin_amdgcn_s_setprio(1);
        #pragma unroll
        for (int ni = 0; ni < 4; ++ni)
            #pragma unroll
            for (int mi = 0; mi < 4; ++mi)
                acc[mi][ni] = __builtin_amdgcn_mfma_f32_16x16x32_f16(
                    af[mi], bf[ni], acc[mi][ni], 0, 0, 0);
        __builtin_amdgcn_s_setprio(0);
        if (ks < 15) {
            #pragma unroll
            for (int ni = 0; ni < 4; ++ni)
                bf[ni] = *(const f16x8*)(bB + (size_t)(ks + 1) * 16384 + ni * 128);
            asm volatile("s_waitcnt lgkmcnt(0)\n\ts_barrier" ::: "memory");
        }
    }

    // epilogue A: relu + b2 -> h2s fp16
    #pragma unroll
    for (int ni = 0; ni < 4; ++ni) {
        int col = 64 * w8 + 16 * ni + ln;
        float bias = b2[col];
        #pragma unroll
        for (int mi = 0; mi < 4; ++mi)
            #pragma unroll
            for (int r = 0; r < 4; ++r) {
                float v = fmaxf(acc[mi][ni][r] + bias, 0.f);
                h2s[16 * mi + 4 * hi + r][col] =
                    __builtin_bit_cast(unsigned short, (_Float16)v);
            }
    }
    __syncthreads();

    // ---- phase B (waves 0-3): nf = h2s @ W3t[node]^T + b3 ----
    if (w8 < 4) {
        const unsigned short* bW3 = W3t + (size_t)node * 32768 + hi * 512 + ln * 8;
        f32x4 accB[4] = {};
        #pragma unroll
        for (int ks = 0; ks < 16; ++ks) {
            f16x8 af = *(const f16x8*)&h2s[16 * w + ln][ks * 32 + hi * 8];
            f16x8 bfB[4];
            #pragma unroll
            for (int ni = 0; ni < 4; ++ni)
                bfB[ni] = *(const f16x8*)(bW3 + ks * 2048 + ni * 128);
            #pragma unroll
            for (int ni = 0; ni < 4; ++ni)
                accB[ni] = __builtin_amdgcn_mfma_f32_16x16x32_f16(
                    af, bfB[ni], accB[ni], 0, 0, 0);
        }
        #pragma unroll
        for (int ni = 0; ni < 4; ++ni) {
            int gnl = 16 * ni + ln;
            int gng = node * 64 + gnl;
            float bias = b3[gng];
            #pragma unroll
            for (int r = 0; r < 4; ++r) {
                int bl = 16 * w + 4 * hi + r;
                float v = accB[ni][r] + bias;
                outN[(size_t)(m0 + bl) * 3200 + gng] = sigmoidf_(v);
                nft[bl][gnl] = __builtin_bit_cast(unsigned short, (_Float16)v);
            }
        }
    }
    __syncthreads();

    // ---- phase C (waves 0-3): Ui/Uj (verbatim) ----
    if (w8 < 4) {
        f16x8 af2[2][4];
        #pragma unroll
        for (int ks2 = 0; ks2 < 2; ++ks2)
            #pragma unroll
            for (int mi = 0; mi < 4; ++mi)
                af2[ks2][mi] = *(const f16x8*)&nft[16 * mi + ln][ks2 * 32 + hi * 8];

        #pragma unroll
        for (int ij = 0; ij < 2; ++ij) {
            const unsigned short* Ep = ij ? E1jh : E1ih;
            unsigned short* Ud = ij ? Ujh : Uih;
            #pragma unroll
            for (int half = 0; half < 2; ++half) {
                f32x4 acc2[4][4] = {};
                #pragma unroll
                for (int ks2 = 0; ks2 < 2; ++ks2) {
                    f16x8 bf2[4];
                    #pragma unroll
                    for (int ni = 0; ni < 4; ++ni)
                        bf2[ni] = *(const f16x8*)(Ep +
                            (size_t)(128 * w + half * 64 + 16 * ni + ln) * 64 +
                            ks2 * 32 + hi * 8);
                    #pragma unroll
                    for (int ni = 0; ni < 4; ++ni)
                        #pragma unroll
                        for (int mi = 0; mi < 4; ++mi)
                            acc2[mi][ni] = __builtin_amdgcn_mfma_f32_16x16x32_f16(
                                af2[ks2][mi], bf2[ni], acc2[mi][ni], 0, 0, 0);
                }
                #pragma unroll
                for (int mi = 0; mi < 4; ++mi) {
                    #pragma unroll
                    for (int r = 0; r < 4; ++r) {
                        int batch = m0 + 16 * mi + 4 * hi + r;
                        #pragma unroll
                        for (int ni = 0; ni < 4; ++ni) {
                            int h = 128 * w + half * 64 + 16 * ni + ln;
                            float v = acc2[mi][ni][r];
                            if (ij == 0) v += Abc[(size_t)batch * 512 + h];
                            Ud[((size_t)batch * 50 + node) * 512 + h] =
                                __builtin_bit_cast(unsigned short, (_Float16)v);
                        }
                    }
                }
            }
        }
    }
}

// ---------------------------------------------------------------------------
// K4: MFMA edge kernel (R12 exact — best measured, 86 µs).
// Single bf register set (VGPR 64 arch + 64 acc), launch_bounds(256,4);
// B direct-from-global (chunk-major E2t), A dbuf LDS (swizzled);
// XCD-bijective 1D swizzle (4992 = 8 x 624).
// ---------------------------------------------------------------------------
__global__ __launch_bounds__(256, 4) void edge_mfma(
    const unsigned short* __restrict__ Ui,   // [B*50,512] fp16 (incl. Abc)
    const unsigned short* __restrict__ Uj,   // [B*50,512] fp16
    const unsigned short* __restrict__ E2t,  // [64 kc][256 g][8] fp16
    const float* __restrict__ c2,
    const float* __restrict__ E3,
    const float* __restrict__ c3p,
    float* __restrict__ outE)                // [B,2450]
{
    __shared__ unsigned short As[2][PTILE * 32];   // 8KB dbuf, swizzled
    __shared__ float c2_s[256], e3_s[256];
    __shared__ int   ii_s[PTILE], jj_s[PTILE];
    __shared__ float red[PTILE][5];

    // XCD-bijective swizzle: 4992 = 8 * 624
    const int gid = blockIdx.x;
    const int nid = (gid & 7) * 624 + (gid >> 3);
    const int b   = nid / NTILES;
    const int p0  = (nid - b * NTILES) * PTILE;

    const int tid = threadIdx.x;
    const int lane = tid & 63;
    const int wid  = tid >> 6;    // g quarter
    const int ln = lane & 15;
    const int hi = lane >> 4;

    c2_s[tid] = c2[tid];
    e3_s[tid] = E3[tid];
    if (tid < PTILE) {
        int p = p0 + tid;
        int i = 0, j = 0;
        if (p < NPAIR) {
            i = p / 49;
            int kk = p - i * 49;
            j = kk + (kk >= i ? 1 : 0);
        }
        ii_s[tid] = i;
        jj_s[tid] = j;
    }
    __syncthreads();

    const unsigned short* UiB = Ui + (size_t)b * MAXN * HIDDEN;
    const unsigned short* UjB = Uj + (size_t)b * MAXN * HIDDEN;

    // A staging: thread -> (row srow, chunk sc) of 64x32 tile
    const int srow = tid >> 2;
    const int sc   = tid & 3;
    const unsigned short* gUi = UiB + (size_t)ii_s[srow] * HIDDEN + sc * 8;
    const unsigned short* gUj = UjB + (size_t)jj_s[srow] * HIDDEN + sc * 8;
    const int swr = srow * 32 + ((sc ^ ((srow >> 1) & 3)) * 8);

    // A fragment read (swizzled): af[mi] at ard + mi*16*32
    const int q   = hi ^ ((ln >> 1) & 3);
    const int ard = ln * 32 + q * 8;

    // B fragment global base: + ks*8192 + ni*128
    const unsigned short* bB = E2t + ((size_t)hi * 256 + 64 * wid + ln) * 8;

    f32x4 acc[4][4] = {};

    // ---- prologue: A(0)->LDS; U(1)->regs; bf(0)->regs
    {
        f16x8 u0 = *(const f16x8*)gUi;
        f16x8 v0 = *(const f16x8*)gUj;
        *(f16x8*)&As[0][swr] = build_e1(u0, v0);
    }
    f16x8 uiN = *(const f16x8*)(gUi + 32);
    f16x8 ujN = *(const f16x8*)(gUj + 32);
    f16x8 bf[4];
    #pragma unroll
    for (int ni = 0; ni < 4; ++ni)
        bf[ni] = *(const f16x8*)(bB + ni * 128);
    asm volatile("s_waitcnt lgkmcnt(0)\n\ts_barrier" ::: "memory");

    #pragma unroll
    for (int ks = 0; ks < 16; ++ks) {
        // build + store A(ks+1) (consumes U(ks+1))
        if (ks < 15)
            *(f16x8*)&As[(ks + 1) & 1][swr] = build_e1(uiN, ujN);
        // prefetch U(ks+2)
        if (ks < 14) {
            uiN = *(const f16x8*)(gUi + 32 * (ks + 2));
            ujN = *(const f16x8*)(gUj + 32 * (ks + 2));
        }
        // af from LDS (post-barrier; 4 ds_read_b128)
        f16x8 af[4];
        #pragma unroll
        for (int mi = 0; mi < 4; ++mi)
            af[mi] = *(const f16x8*)&As[ks & 1][ard + mi * 512];
        // MFMA cluster (consumes bf(ks))
        __builtin_amdgcn_s_setprio(1);
        #pragma unroll
        for (int ni = 0; ni < 4; ++ni)
            #pragma unroll
            for (int mi = 0; mi < 4; ++mi)
                acc[mi][ni] = __builtin_amdgcn_mfma_f32_16x16x32_f16(
                    af[mi], bf[ni], acc[mi][ni], 0, 0, 0);
        __builtin_amdgcn_s_setprio(0);
        // reload bf for ks+1 (single set; issued after last MFMA read)
        if (ks < 15) {
            #pragma unroll
            for (int ni = 0; ni < 4; ++ni)
                bf[ni] = *(const f16x8*)(bB + (size_t)(ks + 1) * 8192 + ni * 128);
            asm volatile("s_waitcnt lgkmcnt(0)\n\ts_barrier" ::: "memory");
        }
    }

    // ---- epilogue
    const float c3v = c3p[0];
    #pragma unroll
    for (int mi = 0; mi < 4; ++mi) {
        #pragma unroll
        for (int r = 0; r < 4; ++r) {
            float part = 0.f;
            #pragma unroll
            for (int ni = 0; ni < 4; ++ni) {
                int g = 64 * wid + 16 * ni + ln;
                float v = fmaxf(acc[mi][ni][r] + c2_s[g], 0.f);
                part = fmaf(v, e3_s[g], part);
            }
            part += __shfl_xor(part, 1);
            part += __shfl_xor(part, 2);
            part += __shfl_xor(part, 4);
            part += __shfl_xor(part, 8);
            if (ln == 0) red[16 * mi + 4 * hi + r][wid] = part;
        }
    }
    __syncthreads();

    if (tid < PTILE) {
        int p = p0 + tid;
        if (p < NPAIR) {
            float s = red[tid][0] + red[tid][1] + red[tid][2] + red[tid][3] + c3v;
            outE[(size_t)b * NPAIR + p] = sigmoidf_(s);
        }
    }
}

// ---------------------------------------------------------------------------
extern "C" void kernel_launch(void* const* d_in, const int* in_sizes, int n_in,
                              void* d_out, int out_size, void* d_ws, size_t ws_size,
                              hipStream_t stream)
{
    const float* z  = (const float*)d_in[0];
    const float* W1 = (const float*)d_in[1];
    const float* b1 = (const float*)d_in[2];
    const float* W2 = (const float*)d_in[3];
    const float* b2 = (const float*)d_in[4];
    const float* W3 = (const float*)d_in[5];
    const float* b3 = (const float*)d_in[6];
    const float* E1 = (const float*)d_in[7];
    const float* c1 = (const float*)d_in[8];
    const float* E2 = (const float*)d_in[9];
    const float* c2 = (const float*)d_in[10];
    const float* E3 = (const float*)d_in[11];
    const float* c3 = (const float*)d_in[12];

    float* out = (float*)d_out;
    float* ws  = (float*)d_ws;

    // workspace layout
    float* Abc = ws;                                        // 65536 f32
    unsigned short* h1h  = (unsigned short*)(Abc + 65536);  // 65536
    unsigned short* W2t  = h1h + 65536;                     // 262144
    unsigned short* W3t  = W2t + 262144;                    // 1638400
    unsigned short* E1ih = W3t + 1638400;                   // 32768
    unsigned short* E1jh = E1ih + 32768;                    // 32768
    unsigned short* E2t  = E1jh + 32768;                    // 131072
    unsigned short* Uih  = E2t + 131072;                    // 3276800
    unsigned short* Ujh  = Uih + 3276800;                   // 3276800

    dim3 blk(256);

    // K1: h1h, Abc, E2t, W2t, W3t, E1ih, E1jh
    prologue_a<<<dim3(272, 4), blk, 0, stream>>>(
        z, W1, b1, E1, c1, E2, W2, W3, E2t, W2t, W3t, E1ih, E1jh, h1h, Abc);

    // K3': fused h2 + nf (sigmoid->out) + Ui/Uj
    nfu_gemm<<<dim3(50, 2), dim3(512), 0, stream>>>(
        h1h, W2t, b2, W3t, b3, E1ih, E1jh, Abc, out, Uih, Ujh);

    // K4: fused edge MLP (1D grid, XCD-swizzled)
    edge_mfma<<<dim3(NTILES * BATCH), blk, 0, stream>>>(
        Uih, Ujh, E2t, c2, E3, c3, out + BATCH * MAXN * NFD);
}